// Round 2
// baseline (1815.002 us; speedup 1.0000x reference)
//
#include <hip/hip_runtime.h>
#include <stdint.h>
#include <math.h>

#define DIM 4096
#define BATCH 1024
#define MAXR 19
#define SPAN 19u

struct RKeys {
  uint32_t skx[MAXR], sky[MAXR];
  uint32_t k1rx, k1ry, k2rx, k2ry, kax, kay;
};

__host__ __device__ __forceinline__ uint32_t rotl32u(uint32_t v, int s) {
  return (v << s) | (v >> (32 - s));
}

// JAX Threefry-2x32, 20 rounds. key=(k0,k1), plaintext=(x0,x1).
__host__ __device__ __forceinline__ void tf2x32(uint32_t k0, uint32_t k1,
                                                uint32_t x0, uint32_t x1,
                                                uint32_t* o0, uint32_t* o1) {
  uint32_t ks2 = k0 ^ k1 ^ 0x1BD11BDAu;
  x0 += k0; x1 += k1;
#define TFR(r) x0 += x1; x1 = rotl32u(x1, (r)); x1 ^= x0;
  TFR(13) TFR(15) TFR(26) TFR(6)
  x0 += k1; x1 += ks2 + 1u;
  TFR(17) TFR(29) TFR(16) TFR(24)
  x0 += ks2; x1 += k0 + 2u;
  TFR(13) TFR(15) TFR(26) TFR(6)
  x0 += k0; x1 += k1 + 3u;
  TFR(17) TFR(29) TFR(16) TFR(24)
  x0 += k1; x1 += ks2 + 4u;
  TFR(13) TFR(15) TFR(26) TFR(6)
  x0 += ks2; x1 += k0 + 5u;
#undef TFR
  *o0 = x0; *o1 = x1;
}

__device__ __forceinline__ float bits_to_unit(uint32_t bits) {
  // JAX uniform [0,1): mantissa trick, exact.
  return __uint_as_float((bits >> 9) | 0x3f800000u) - 1.0f;
}

__device__ __forceinline__ int radius_for_row(const RKeys& K, int row) {
  // jax.random.randint(k_rad,(B,1),1,20), partitionable mode.
  uint32_t h0, h1, l0, l1;
  tf2x32(K.k1rx, K.k1ry, 0u, (uint32_t)row, &h0, &h1);
  tf2x32(K.k2rx, K.k2ry, 0u, (uint32_t)row, &l0, &l1);
  uint32_t hb = h0 ^ h1, lb = l0 ^ l1;
  // multiplier = ((2^16 % 19)^2) % 19 = 6
  return 1 + (int)((((hb % SPAN) * 6u) + (lb % SPAN)) % SPAN);
}

// ---------------- GEMM: C = A @ W + b   (A: [1024,4096] f32, W: [4096,4096]) ----
__global__ __launch_bounds__(256)
void gemm_bias_kernel(const float* __restrict__ A, const float* __restrict__ W,
                      const float* __restrict__ bvec, float* __restrict__ C) {
  __shared__ float As[16][64];
  __shared__ float Bs[16][64];
  const int tid = threadIdx.x;
  const int tx = tid & 15, ty = tid >> 4;
  const int row0 = blockIdx.y * 64, col0 = blockIdx.x * 64;
  const int ar = tid >> 2, ak = (tid & 3) << 2;
  const int bk = tid >> 4, bn = (tid & 15) << 2;
  float acc[4][4] = {{0.f,0.f,0.f,0.f},{0.f,0.f,0.f,0.f},
                     {0.f,0.f,0.f,0.f},{0.f,0.f,0.f,0.f}};
  for (int k0 = 0; k0 < DIM; k0 += 16) {
    float4 av = *reinterpret_cast<const float4*>(&A[(size_t)(row0 + ar) * DIM + k0 + ak]);
    float4 bv = *reinterpret_cast<const float4*>(&W[(size_t)(k0 + bk) * DIM + col0 + bn]);
    __syncthreads();
    As[ak + 0][ar] = av.x; As[ak + 1][ar] = av.y;
    As[ak + 2][ar] = av.z; As[ak + 3][ar] = av.w;
    *reinterpret_cast<float4*>(&Bs[bk][bn]) = bv;
    __syncthreads();
#pragma unroll
    for (int kk = 0; kk < 16; ++kk) {
      float4 a4 = *reinterpret_cast<const float4*>(&As[kk][ty << 2]);
      float4 b4 = *reinterpret_cast<const float4*>(&Bs[kk][tx << 2]);
      acc[0][0] = fmaf(a4.x, b4.x, acc[0][0]);
      acc[0][1] = fmaf(a4.x, b4.y, acc[0][1]);
      acc[0][2] = fmaf(a4.x, b4.z, acc[0][2]);
      acc[0][3] = fmaf(a4.x, b4.w, acc[0][3]);
      acc[1][0] = fmaf(a4.y, b4.x, acc[1][0]);
      acc[1][1] = fmaf(a4.y, b4.y, acc[1][1]);
      acc[1][2] = fmaf(a4.y, b4.z, acc[1][2]);
      acc[1][3] = fmaf(a4.y, b4.w, acc[1][3]);
      acc[2][0] = fmaf(a4.z, b4.x, acc[2][0]);
      acc[2][1] = fmaf(a4.z, b4.y, acc[2][1]);
      acc[2][2] = fmaf(a4.z, b4.z, acc[2][2]);
      acc[2][3] = fmaf(a4.z, b4.w, acc[2][3]);
      acc[3][0] = fmaf(a4.w, b4.x, acc[3][0]);
      acc[3][1] = fmaf(a4.w, b4.y, acc[3][1]);
      acc[3][2] = fmaf(a4.w, b4.z, acc[3][2]);
      acc[3][3] = fmaf(a4.w, b4.w, acc[3][3]);
    }
  }
#pragma unroll
  for (int i = 0; i < 4; ++i) {
#pragma unroll
    for (int j = 0; j < 4; ++j) {
      int r = row0 + (ty << 2) + i, c = col0 + (tx << 2) + j;
      C[(size_t)r * DIM + c] = acc[i][j] + bvec[c];
    }
  }
}

// ---------------- forward scan: categorical flips + fwd logprob -----------------
__global__ __launch_bounds__(256)
void scan_kernel(const float* __restrict__ x, const float* __restrict__ bvec,
                 const float* __restrict__ gx, float* __restrict__ y,
                 int* __restrict__ idxs, float* __restrict__ logfwd, RKeys K) {
  const int row = blockIdx.x, tid = threadIdx.x;
  __shared__ float s_gx[DIM];
  __shared__ float s_delta[DIM];
  __shared__ float r_z[256];
  __shared__ int   r_i[256];
  __shared__ float r_m[256];
  __shared__ float r_s[256];
  __shared__ float s_sel[MAXR];
  __shared__ float s_scorex;

  float sp = 0.f;
  for (int k = tid; k < DIM; k += 256) {
    float g = gx[(size_t)row * DIM + k];
    float xv = x[(size_t)row * DIM + k];
    s_gx[k] = g;
    s_delta[k] = 1.0f - 2.0f * xv;
    sp += xv * (g + bvec[k]);  // score_x = 0.5*x.(Wx) + x.b = 0.5*sum x*(gx+b)
  }
  r_s[tid] = sp; __syncthreads();
  for (int s = 128; s > 0; s >>= 1) { if (tid < s) r_s[tid] += r_s[tid + s]; __syncthreads(); }
  if (tid == 0) s_scorex = 0.5f * r_s[0];
  const int radius = radius_for_row(K, row);
  __syncthreads();

  for (int t = 0; t < MAXR; ++t) {
    const uint32_t skx = K.skx[t], sky = K.sky[t];
    float bz = -INFINITY; int bi = 0x7fffffff; float ml = -INFINITY;
    for (int k = tid; k < DIM; k += 256) {
      float logit = 0.5f * s_delta[k] * s_gx[k];   // exact given gx
      uint32_t o0, o1;
      tf2x32(skx, sky, 0u, (uint32_t)(row * DIM + k), &o0, &o1);
      float f = bits_to_unit(o0 ^ o1);
      float uu = (f == 0.0f) ? 1.17549435e-38f : f;  // max(tiny, f)
      float t1 = (float)log((double)uu);
      float t3 = (float)log((double)(-t1));
      float z = (-t3) + logit;                      // gumbel + logits
      if (z > bz || (z == bz && k < bi)) { bz = z; bi = k; }
      ml = fmaxf(ml, logit);
    }
    r_z[tid] = bz; r_i[tid] = bi; r_m[tid] = ml;
    __syncthreads();
    for (int s = 128; s > 0; s >>= 1) {
      if (tid < s) {
        float oz = r_z[tid + s]; int oi = r_i[tid + s];
        if (oz > r_z[tid] || (oz == r_z[tid] && oi < r_i[tid])) { r_z[tid] = oz; r_i[tid] = oi; }
        r_m[tid] = fmaxf(r_m[tid], r_m[tid + s]);
      }
      __syncthreads();
    }
    const int idx = r_i[0];
    const float maxl = r_m[0];
    float ssum = 0.f;
    for (int k = tid; k < DIM; k += 256) {
      float logit = 0.5f * s_delta[k] * s_gx[k];
      ssum += (float)exp((double)(logit - maxl));
    }
    __syncthreads();
    r_s[tid] = ssum; __syncthreads();
    for (int s = 128; s > 0; s >>= 1) { if (tid < s) r_s[tid] += r_s[tid + s]; __syncthreads(); }
    if (tid == 0) {
      float logS = (float)log((double)r_s[0]);
      float li = 0.5f * s_delta[idx] * s_gx[idx];
      s_sel[t] = (li - maxl) - logS;               // log_softmax picked value
      idxs[row * MAXR + t] = idx;
    }
    __syncthreads();
    if (tid == 0 && t < radius) s_delta[idx] = -s_delta[idx];  // masked flip
    __syncthreads();
  }

  for (int k = tid; k < DIM; k += 256)
    y[(size_t)row * DIM + k] = (s_delta[k] < 0.f) ? 1.0f : 0.0f;
  if (tid == 0) {
    float a = 0.f;
    for (int t = 0; t < MAXR; ++t) if (t < radius) a += s_sel[t];
    logfwd[row] = a + s_scorex;
  }
}

// ---------------- backward logprob + accept/select ------------------------------
__global__ __launch_bounds__(256)
void bwd_kernel(const float* __restrict__ x, const float* __restrict__ bvec,
                const float* __restrict__ gy, float* __restrict__ y_out,
                const int* __restrict__ idxs, const float* __restrict__ logfwd,
                RKeys K) {
  const int row = blockIdx.x, tid = threadIdx.x;
  __shared__ float s_gy[DIM];
  __shared__ float s_delta[DIM];
  __shared__ float r_m[256];
  __shared__ float r_s[256];
  __shared__ float s_sel[MAXR];
  __shared__ float s_scorey;
  __shared__ int s_acc;

  float sp = 0.f;
  for (int k = tid; k < DIM; k += 256) {
    float g = gy[(size_t)row * DIM + k];
    float yv = y_out[(size_t)row * DIM + k];
    s_gy[k] = g;
    s_delta[k] = 1.0f - 2.0f * yv;
    sp += yv * (g + bvec[k]);
  }
  r_s[tid] = sp; __syncthreads();
  for (int s = 128; s > 0; s >>= 1) { if (tid < s) r_s[tid] += r_s[tid + s]; __syncthreads(); }
  if (tid == 0) s_scorey = 0.5f * r_s[0];
  const int radius = radius_for_row(K, row);
  __syncthreads();

  // traj_bwd[t] = delta-state AFTER update t; start from y (t=18) and undo flips.
  for (int t = MAXR - 1; t >= 0; --t) {
    const int idx = idxs[row * MAXR + t];
    float ml = -INFINITY;
    for (int k = tid; k < DIM; k += 256)
      ml = fmaxf(ml, 0.5f * s_delta[k] * s_gy[k]);
    r_m[tid] = ml; __syncthreads();
    for (int s = 128; s > 0; s >>= 1) { if (tid < s) r_m[tid] = fmaxf(r_m[tid], r_m[tid + s]); __syncthreads(); }
    const float maxl = r_m[0];
    float ssum = 0.f;
    for (int k = tid; k < DIM; k += 256) {
      float logit = 0.5f * s_delta[k] * s_gy[k];
      ssum += (float)exp((double)(logit - maxl));
    }
    __syncthreads();
    r_s[tid] = ssum; __syncthreads();
    for (int s = 128; s > 0; s >>= 1) { if (tid < s) r_s[tid] += r_s[tid + s]; __syncthreads(); }
    if (tid == 0) {
      float logS = (float)log((double)r_s[0]);
      float li = 0.5f * s_delta[idx] * s_gy[idx];
      s_sel[t] = (li - maxl) - logS;
    }
    __syncthreads();
    if (tid == 0 && t < radius) s_delta[idx] = -s_delta[idx];  // undo flip t
    __syncthreads();
  }

  if (tid == 0) {
    float bsum = 0.f;
    for (int t = 0; t < MAXR; ++t) if (t < radius) bsum += s_sel[t];
    float la = (bsum + s_scorey) - logfwd[row];
    uint32_t a, b2;
    tf2x32(K.kax, K.kay, 0u, (uint32_t)row, &a, &b2);
    float u = bits_to_unit(a ^ b2);
    s_acc = ((float)exp((double)la) >= u) ? 1 : 0;
  }
  __syncthreads();
  const int acc = s_acc;
  for (int k = tid; k < DIM; k += 256) {
    size_t i = (size_t)row * DIM + k;
    float yv = y_out[i];
    y_out[i] = acc ? yv : x[i];
  }
}

extern "C" void kernel_launch(void* const* d_in, const int* in_sizes, int n_in,
                              void* d_out, int out_size, void* d_ws, size_t ws_size,
                              hipStream_t stream) {
  const float* x = (const float*)d_in[0];
  const float* W = (const float*)d_in[1];
  const float* bvec = (const float*)d_in[2];
  float* out = (float*)d_out;                 // holds y, then final new_x

  // Workspace layout (~16.1 MB): one grad buffer reused for gx then gy,
  // since gx is dead after scan_kernel.
  float* grad = (float*)d_ws;                 // 16 MB
  float* logfwd = grad + (size_t)BATCH * DIM; // 4 KB
  int* idxs = (int*)(logfwd + BATCH);         // 76 KB

  // Host-side key derivation (jax.random.key(42), partitionable threefry).
  RKeys K;
  uint32_t krx, kry, ksx, ksy;
  tf2x32(0u, 42u, 0u, 0u, &krx, &kry);        // k_rad
  tf2x32(0u, 42u, 0u, 1u, &ksx, &ksy);        // k_steps
  tf2x32(0u, 42u, 0u, 2u, &K.kax, &K.kay);    // k_acc
  tf2x32(krx, kry, 0u, 0u, &K.k1rx, &K.k1ry); // randint internal split
  tf2x32(krx, kry, 0u, 1u, &K.k2rx, &K.k2ry);
  for (int t = 0; t < MAXR; ++t)
    tf2x32(ksx, ksy, 0u, (uint32_t)t, &K.skx[t], &K.sky[t]);

  dim3 gg(DIM / 64, BATCH / 64);
  gemm_bias_kernel<<<gg, 256, 0, stream>>>(x, W, bvec, grad);       // grad_x
  scan_kernel<<<BATCH, 256, 0, stream>>>(x, bvec, grad, out, idxs, logfwd, K);
  gemm_bias_kernel<<<gg, 256, 0, stream>>>(out, W, bvec, grad);     // grad_y
  bwd_kernel<<<BATCH, 256, 0, stream>>>(x, bvec, grad, out, idxs, logfwd, K);
}

// Round 3
// 695.451 us; speedup vs baseline: 2.6098x; 2.6098x over previous
//
#include <hip/hip_runtime.h>
#include <stdint.h>
#include <math.h>

#define DIM 4096
#define BATCH 1024
#define MAXR 19
#define SPAN 19u

typedef _Float16 half8 __attribute__((ext_vector_type(8)));
typedef _Float16 half4 __attribute__((ext_vector_type(4)));
typedef float f32x4 __attribute__((ext_vector_type(4)));

struct RKeys {
  uint32_t skx[MAXR], sky[MAXR];
  uint32_t k1rx, k1ry, k2rx, k2ry, kax, kay;
};

__host__ __device__ __forceinline__ uint32_t rotl32u(uint32_t v, int s) {
  return (v << s) | (v >> (32 - s));
}

// JAX Threefry-2x32, 20 rounds. key=(k0,k1), plaintext=(x0,x1).
__host__ __device__ __forceinline__ void tf2x32(uint32_t k0, uint32_t k1,
                                                uint32_t x0, uint32_t x1,
                                                uint32_t* o0, uint32_t* o1) {
  uint32_t ks2 = k0 ^ k1 ^ 0x1BD11BDAu;
  x0 += k0; x1 += k1;
#define TFR(r) x0 += x1; x1 = rotl32u(x1, (r)); x1 ^= x0;
  TFR(13) TFR(15) TFR(26) TFR(6)
  x0 += k1; x1 += ks2 + 1u;
  TFR(17) TFR(29) TFR(16) TFR(24)
  x0 += ks2; x1 += k0 + 2u;
  TFR(13) TFR(15) TFR(26) TFR(6)
  x0 += k0; x1 += k1 + 3u;
  TFR(17) TFR(29) TFR(16) TFR(24)
  x0 += k1; x1 += ks2 + 4u;
  TFR(13) TFR(15) TFR(26) TFR(6)
  x0 += ks2; x1 += k0 + 5u;
#undef TFR
  *o0 = x0; *o1 = x1;
}

__device__ __forceinline__ float bits_to_unit(uint32_t bits) {
  return __uint_as_float((bits >> 9) | 0x3f800000u) - 1.0f;
}

__device__ __forceinline__ int radius_for_row(const RKeys& K, int row) {
  uint32_t h0, h1, l0, l1;
  tf2x32(K.k1rx, K.k1ry, 0u, (uint32_t)row, &h0, &h1);
  tf2x32(K.k2rx, K.k2ry, 0u, (uint32_t)row, &l0, &l1);
  uint32_t hb = h0 ^ h1, lb = l0 ^ l1;
  return 1 + (int)((((hb % SPAN) * 6u) + (lb % SPAN)) % SPAN);
}

// ---------------- W split: Wh = f16(W); Wl = f16((W - Wh)*256) ------------------
__global__ __launch_bounds__(256)
void split_w_kernel(const float* __restrict__ W, _Float16* __restrict__ Wh,
                    _Float16* __restrict__ Wl) {
  size_t i = ((size_t)blockIdx.x * 256 + threadIdx.x) * 4;
  float4 w = *reinterpret_cast<const float4*>(&W[i]);
  _Float16 h0 = (_Float16)w.x, h1 = (_Float16)w.y, h2 = (_Float16)w.z, h3 = (_Float16)w.w;
  half4 hv = {h0, h1, h2, h3};
  half4 lv = {(_Float16)((w.x - (float)h0) * 256.f),
              (_Float16)((w.y - (float)h1) * 256.f),
              (_Float16)((w.z - (float)h2) * 256.f),
              (_Float16)((w.w - (float)h3) * 256.f)};
  *reinterpret_cast<half4*>(&Wh[i]) = hv;
  *reinterpret_cast<half4*>(&Wl[i]) = lv;
}

__global__ __launch_bounds__(256)
void conv_f16_kernel(const float* __restrict__ in, _Float16* __restrict__ out) {
  size_t i = ((size_t)blockIdx.x * 256 + threadIdx.x) * 4;
  float4 v = *reinterpret_cast<const float4*>(&in[i]);
  half4 h = {(_Float16)v.x, (_Float16)v.y, (_Float16)v.z, (_Float16)v.w};
  *reinterpret_cast<half4*>(&out[i]) = h;
}

// ---------------- f16 dual-split MFMA GEMM: C = A@Wh + A@Wl/256 + b -------------
// A [1024][4096] f16 (exact 0/1). W symmetric => B-tile staged n-major from W rows.
#define GBM 64
#define GBN 64
#define GBK 64
__global__ __launch_bounds__(256)
void gemm_f16_kernel(const _Float16* __restrict__ A, const _Float16* __restrict__ Bh,
                     const _Float16* __restrict__ Bl, const float* __restrict__ bias,
                     float* __restrict__ C) {
  __shared__ _Float16 As[GBM][GBK];
  __shared__ _Float16 Bhs[GBN][GBK];   // [n][k]
  __shared__ _Float16 Bls[GBN][GBK];
  const int tid = threadIdx.x;
  const int lane = tid & 63, w = tid >> 6;
  const int wr = w >> 1, wc = w & 1;               // 2x2 waves, each 32x32 out
  const int m0 = blockIdx.y * GBM, n0 = blockIdx.x * GBN;
  const int sr = tid >> 2, sc = (tid & 3) << 4;    // staging: row, 16-f16 chunk

  f32x4 acc_h[2][2] = {};
  f32x4 acc_l[2][2] = {};

  for (int k0 = 0; k0 < DIM; k0 += GBK) {
    half8 ra0 = *reinterpret_cast<const half8*>(&A[(size_t)(m0 + sr) * DIM + k0 + sc]);
    half8 ra1 = *reinterpret_cast<const half8*>(&A[(size_t)(m0 + sr) * DIM + k0 + sc + 8]);
    half8 rh0 = *reinterpret_cast<const half8*>(&Bh[(size_t)(n0 + sr) * DIM + k0 + sc]);
    half8 rh1 = *reinterpret_cast<const half8*>(&Bh[(size_t)(n0 + sr) * DIM + k0 + sc + 8]);
    half8 rl0 = *reinterpret_cast<const half8*>(&Bl[(size_t)(n0 + sr) * DIM + k0 + sc]);
    half8 rl1 = *reinterpret_cast<const half8*>(&Bl[(size_t)(n0 + sr) * DIM + k0 + sc + 8]);
    __syncthreads();
    *reinterpret_cast<half8*>(&As[sr][sc]) = ra0;
    *reinterpret_cast<half8*>(&As[sr][sc + 8]) = ra1;
    *reinterpret_cast<half8*>(&Bhs[sr][sc]) = rh0;
    *reinterpret_cast<half8*>(&Bhs[sr][sc + 8]) = rh1;
    *reinterpret_cast<half8*>(&Bls[sr][sc]) = rl0;
    *reinterpret_cast<half8*>(&Bls[sr][sc + 8]) = rl1;
    __syncthreads();
#pragma unroll
    for (int ks = 0; ks < 2; ++ks) {
      const int kb = ks * 32 + (lane >> 4) * 8;
      half8 af[2], bhf[2], blf[2];
#pragma unroll
      for (int i = 0; i < 2; ++i) {
        af[i]  = *reinterpret_cast<const half8*>(&As[wr * 32 + i * 16 + (lane & 15)][kb]);
        bhf[i] = *reinterpret_cast<const half8*>(&Bhs[wc * 32 + i * 16 + (lane & 15)][kb]);
        blf[i] = *reinterpret_cast<const half8*>(&Bls[wc * 32 + i * 16 + (lane & 15)][kb]);
      }
#pragma unroll
      for (int mi = 0; mi < 2; ++mi)
#pragma unroll
        for (int ni = 0; ni < 2; ++ni) {
          acc_h[mi][ni] = __builtin_amdgcn_mfma_f32_16x16x32_f16(af[mi], bhf[ni], acc_h[mi][ni], 0, 0, 0);
          acc_l[mi][ni] = __builtin_amdgcn_mfma_f32_16x16x32_f16(af[mi], blf[ni], acc_l[mi][ni], 0, 0, 0);
        }
    }
  }
  const int cr = (lane >> 4) * 2 * 2, cc = lane & 15;  // (lane>>4)*4
#pragma unroll
  for (int mi = 0; mi < 2; ++mi)
#pragma unroll
    for (int ni = 0; ni < 2; ++ni) {
      const int col = n0 + wc * 32 + ni * 16 + cc;
      const float bv = bias[col];
#pragma unroll
      for (int r = 0; r < 4; ++r) {
        const int rrow = m0 + wr * 32 + mi * 16 + cr + r;
        C[(size_t)rrow * DIM + col] = acc_h[mi][ni][r] + acc_l[mi][ni][r] * (1.f / 256.f) + bv;
      }
    }
}

// ---------------- f32 fallback GEMM (proven round-2 kernel) ---------------------
__global__ __launch_bounds__(256)
void gemm_bias_kernel(const float* __restrict__ A, const float* __restrict__ W,
                      const float* __restrict__ bvec, float* __restrict__ C) {
  __shared__ float Asf[16][64];
  __shared__ float Bsf[16][64];
  const int tid = threadIdx.x;
  const int tx = tid & 15, ty = tid >> 4;
  const int row0 = blockIdx.y * 64, col0 = blockIdx.x * 64;
  const int ar = tid >> 2, ak = (tid & 3) << 2;
  const int bk = tid >> 4, bn = (tid & 15) << 2;
  float acc[4][4] = {};
  for (int k0 = 0; k0 < DIM; k0 += 16) {
    float4 av = *reinterpret_cast<const float4*>(&A[(size_t)(row0 + ar) * DIM + k0 + ak]);
    float4 bv = *reinterpret_cast<const float4*>(&W[(size_t)(k0 + bk) * DIM + col0 + bn]);
    __syncthreads();
    Asf[ak + 0][ar] = av.x; Asf[ak + 1][ar] = av.y;
    Asf[ak + 2][ar] = av.z; Asf[ak + 3][ar] = av.w;
    *reinterpret_cast<float4*>(&Bsf[bk][bn]) = bv;
    __syncthreads();
#pragma unroll
    for (int kk = 0; kk < 16; ++kk) {
      float4 a4 = *reinterpret_cast<const float4*>(&Asf[kk][ty << 2]);
      float4 b4 = *reinterpret_cast<const float4*>(&Bsf[kk][tx << 2]);
#pragma unroll
      for (int i = 0; i < 4; ++i) {
        float ai = (i == 0) ? a4.x : (i == 1) ? a4.y : (i == 2) ? a4.z : a4.w;
        acc[i][0] = fmaf(ai, b4.x, acc[i][0]);
        acc[i][1] = fmaf(ai, b4.y, acc[i][1]);
        acc[i][2] = fmaf(ai, b4.z, acc[i][2]);
        acc[i][3] = fmaf(ai, b4.w, acc[i][3]);
      }
    }
  }
#pragma unroll
  for (int i = 0; i < 4; ++i)
#pragma unroll
    for (int j = 0; j < 4; ++j) {
      int r = row0 + (ty << 2) + i, c = col0 + (tx << 2) + j;
      C[(size_t)r * DIM + c] = acc[i][j] + bvec[c];
    }
}

// ---------------- forward scan ---------------------------------------------------
__global__ __launch_bounds__(256)
void scan_kernel(const float* __restrict__ x, const float* __restrict__ bvec,
                 const float* __restrict__ gx, float* __restrict__ y,
                 int* __restrict__ idxs, float* __restrict__ logfwd, RKeys K) {
  const int row = blockIdx.x, tid = threadIdx.x;
  const int wid = tid >> 6;
  __shared__ float s_l[DIM];
  __shared__ float s_g[DIM];
  __shared__ float r_f[4];
  __shared__ int   r_i[4];
  __shared__ float s_bcast;

  const float* gxr = gx + (size_t)row * DIM;
  const float* xr  = x + (size_t)row * DIM;
  float* yr = y + (size_t)row * DIM;

  float sp = 0.f, ml = -INFINITY;
  for (int k4 = tid * 4; k4 < DIM; k4 += 1024) {
    float4 g4 = *reinterpret_cast<const float4*>(&gxr[k4]);
    float4 x4 = *reinterpret_cast<const float4*>(&xr[k4]);
    float4 b4 = *reinterpret_cast<const float4*>(&bvec[k4]);
    float4 l4;
    l4.x = 0.5f * (1.f - 2.f * x4.x) * g4.x;
    l4.y = 0.5f * (1.f - 2.f * x4.y) * g4.y;
    l4.z = 0.5f * (1.f - 2.f * x4.z) * g4.z;
    l4.w = 0.5f * (1.f - 2.f * x4.w) * g4.w;
    *reinterpret_cast<float4*>(&s_g[k4]) = g4;
    *reinterpret_cast<float4*>(&s_l[k4]) = l4;
    sp += x4.x * (g4.x + b4.x) + x4.y * (g4.y + b4.y) +
          x4.z * (g4.z + b4.z) + x4.w * (g4.w + b4.w);
    ml = fmaxf(ml, fmaxf(fmaxf(l4.x, l4.y), fmaxf(l4.z, l4.w)));
  }
  // score reduction
#pragma unroll
  for (int s = 1; s < 64; s <<= 1) sp += __shfl_xor(sp, s, 64);
  if ((tid & 63) == 0) r_f[wid] = sp;
  __syncthreads();
  float score_x = 0.f;
  if (tid == 0) score_x = 0.5f * (r_f[0] + r_f[1] + r_f[2] + r_f[3]);
  // max reduction
#pragma unroll
  for (int s = 1; s < 64; s <<= 1) ml = fmaxf(ml, __shfl_xor(ml, s, 64));
  __syncthreads();
  if ((tid & 63) == 0) r_f[wid] = ml;
  __syncthreads();
  if (tid == 0) s_bcast = fmaxf(fmaxf(r_f[0], r_f[1]), fmaxf(r_f[2], r_f[3]));
  __syncthreads();
  const float m = s_bcast;
  // initial denominator
  float ssum = 0.f;
  for (int k4 = tid * 4; k4 < DIM; k4 += 1024) {
    float4 l4 = *reinterpret_cast<const float4*>(&s_l[k4]);
    ssum += expf(l4.x - m) + expf(l4.y - m) + expf(l4.z - m) + expf(l4.w - m);
  }
#pragma unroll
  for (int s = 1; s < 64; s <<= 1) ssum += __shfl_xor(ssum, s, 64);
  __syncthreads();
  if ((tid & 63) == 0) r_f[wid] = ssum;
  __syncthreads();
  float S_cur = 0.f, acc_lp = 0.f;
  if (tid == 0) S_cur = r_f[0] + r_f[1] + r_f[2] + r_f[3];

  const int radius = radius_for_row(K, row);
  const uint32_t base = (uint32_t)row * DIM;
  __syncthreads();

  for (int t = 0; t < radius; ++t) {
    const uint32_t skx = K.skx[t], sky = K.sky[t];
    float bz = -INFINITY; int bi = 0x7fffffff;
    for (int k = tid; k < DIM; k += 256) {
      float logit = s_l[k];
      uint32_t o0, o1;
      tf2x32(skx, sky, 0u, base + (uint32_t)k, &o0, &o1);
      float f = bits_to_unit(o0 ^ o1);
      float uu = (f == 0.0f) ? 1.17549435e-38f : f;
      float t1 = logf(uu);
      float z = -logf(-t1) + logit;
      if (z > bz || (z == bz && k < bi)) { bz = z; bi = k; }
    }
#pragma unroll
    for (int s = 1; s < 64; s <<= 1) {
      float oz = __shfl_xor(bz, s, 64);
      int oi = __shfl_xor(bi, s, 64);
      if (oz > bz || (oz == bz && oi < bi)) { bz = oz; bi = oi; }
    }
    if ((tid & 63) == 0) { r_f[wid] = bz; r_i[wid] = bi; }
    __syncthreads();
    if (tid == 0) {
      float fz = r_f[0]; int fi = r_i[0];
#pragma unroll
      for (int w2 = 1; w2 < 4; ++w2) {
        float oz = r_f[w2]; int oi = r_i[w2];
        if (oz > fz || (oz == fz && oi < fi)) { fz = oz; fi = oi; }
      }
      float l = s_l[fi];
      acc_lp += (l - m) - logf(S_cur);
      S_cur += expf(-l - m) - expf(l - m);
      s_l[fi] = -l;
      idxs[row * MAXR + t] = fi;
    }
    __syncthreads();
  }

  for (int k4 = tid * 4; k4 < DIM; k4 += 1024) {
    float4 l4 = *reinterpret_cast<const float4*>(&s_l[k4]);
    float4 g4 = *reinterpret_cast<const float4*>(&s_g[k4]);
    float4 y4;
    y4.x = (float)(((__float_as_uint(l4.x) ^ __float_as_uint(g4.x)) >> 31) & 1u);
    y4.y = (float)(((__float_as_uint(l4.y) ^ __float_as_uint(g4.y)) >> 31) & 1u);
    y4.z = (float)(((__float_as_uint(l4.z) ^ __float_as_uint(g4.z)) >> 31) & 1u);
    y4.w = (float)(((__float_as_uint(l4.w) ^ __float_as_uint(g4.w)) >> 31) & 1u);
    *reinterpret_cast<float4*>(&yr[k4]) = y4;
  }
  if (tid == 0) logfwd[row] = acc_lp + score_x;
}

// ---------------- backward logprob + accept/select ------------------------------
__global__ __launch_bounds__(256)
void bwd_kernel(const float* __restrict__ x, const float* __restrict__ bvec,
                const float* __restrict__ gy, float* __restrict__ y_out,
                const int* __restrict__ idxs, const float* __restrict__ logfwd,
                RKeys K) {
  const int row = blockIdx.x, tid = threadIdx.x;
  const int wid = tid >> 6;
  __shared__ float s_l[DIM];
  __shared__ float r_f[4];
  __shared__ float s_bcast;
  __shared__ int s_acc;

  const float* gyr = gy + (size_t)row * DIM;
  float* yr = y_out + (size_t)row * DIM;
  const float* xr = x + (size_t)row * DIM;

  float sp = 0.f, ml = -INFINITY;
  for (int k4 = tid * 4; k4 < DIM; k4 += 1024) {
    float4 g4 = *reinterpret_cast<const float4*>(&gyr[k4]);
    float4 y4 = *reinterpret_cast<const float4*>(&yr[k4]);
    float4 b4 = *reinterpret_cast<const float4*>(&bvec[k4]);
    float4 l4;
    l4.x = 0.5f * (1.f - 2.f * y4.x) * g4.x;
    l4.y = 0.5f * (1.f - 2.f * y4.y) * g4.y;
    l4.z = 0.5f * (1.f - 2.f * y4.z) * g4.z;
    l4.w = 0.5f * (1.f - 2.f * y4.w) * g4.w;
    *reinterpret_cast<float4*>(&s_l[k4]) = l4;
    sp += y4.x * (g4.x + b4.x) + y4.y * (g4.y + b4.y) +
          y4.z * (g4.z + b4.z) + y4.w * (g4.w + b4.w);
    ml = fmaxf(ml, fmaxf(fmaxf(l4.x, l4.y), fmaxf(l4.z, l4.w)));
  }
#pragma unroll
  for (int s = 1; s < 64; s <<= 1) sp += __shfl_xor(sp, s, 64);
  if ((tid & 63) == 0) r_f[wid] = sp;
  __syncthreads();
  float score_y = 0.f;
  if (tid == 0) score_y = 0.5f * (r_f[0] + r_f[1] + r_f[2] + r_f[3]);
#pragma unroll
  for (int s = 1; s < 64; s <<= 1) ml = fmaxf(ml, __shfl_xor(ml, s, 64));
  __syncthreads();
  if ((tid & 63) == 0) r_f[wid] = ml;
  __syncthreads();
  if (tid == 0) s_bcast = fmaxf(fmaxf(r_f[0], r_f[1]), fmaxf(r_f[2], r_f[3]));
  __syncthreads();
  const float m = s_bcast;
  float ssum = 0.f;
  for (int k4 = tid * 4; k4 < DIM; k4 += 1024) {
    float4 l4 = *reinterpret_cast<const float4*>(&s_l[k4]);
    ssum += expf(l4.x - m) + expf(l4.y - m) + expf(l4.z - m) + expf(l4.w - m);
  }
#pragma unroll
  for (int s = 1; s < 64; s <<= 1) ssum += __shfl_xor(ssum, s, 64);
  __syncthreads();
  if ((tid & 63) == 0) r_f[wid] = ssum;
  __syncthreads();

  if (tid == 0) {
    float S_cur = r_f[0] + r_f[1] + r_f[2] + r_f[3];
    const int radius = radius_for_row(K, row);
    float acc_lp = 0.f;
    for (int t = radius - 1; t >= 0; --t) {
      int idx = idxs[row * MAXR + t];
      float l = s_l[idx];
      acc_lp += (l - m) - logf(S_cur);
      S_cur += expf(-l - m) - expf(l - m);
      s_l[idx] = -l;
    }
    float la = (acc_lp + score_y) - logfwd[row];
    uint32_t a, b2;
    tf2x32(K.kax, K.kay, 0u, (uint32_t)row, &a, &b2);
    float u = bits_to_unit(a ^ b2);
    s_acc = (expf(la) >= u) ? 1 : 0;
  }
  __syncthreads();
  if (!s_acc) {
    for (int k4 = tid * 4; k4 < DIM; k4 += 1024)
      *reinterpret_cast<float4*>(&yr[k4]) = *reinterpret_cast<const float4*>(&xr[k4]);
  }
}

extern "C" void kernel_launch(void* const* d_in, const int* in_sizes, int n_in,
                              void* d_out, int out_size, void* d_ws, size_t ws_size,
                              hipStream_t stream) {
  const float* x = (const float*)d_in[0];
  const float* W = (const float*)d_in[1];
  const float* bvec = (const float*)d_in[2];
  float* out = (float*)d_out;

  RKeys K;
  uint32_t krx, kry, ksx, ksy;
  tf2x32(0u, 42u, 0u, 0u, &krx, &kry);
  tf2x32(0u, 42u, 0u, 1u, &ksx, &ksy);
  tf2x32(0u, 42u, 0u, 2u, &K.kax, &K.kay);
  tf2x32(krx, kry, 0u, 0u, &K.k1rx, &K.k1ry);
  tf2x32(krx, kry, 0u, 1u, &K.k2rx, &K.k2ry);
  for (int t = 0; t < MAXR; ++t)
    tf2x32(ksx, ksy, 0u, (uint32_t)t, &K.skx[t], &K.sky[t]);

  const size_t szW16 = (size_t)DIM * DIM * 2;       // 32 MB
  const size_t szA16 = (size_t)BATCH * DIM * 2;     // 8 MB
  const size_t szGrad = (size_t)BATCH * DIM * 4;    // 16 MB
  const size_t need_f16 = 2 * szW16 + szA16 + szGrad + BATCH * 4 + (size_t)BATCH * MAXR * 4;

  if (ws_size >= need_f16) {
    _Float16* Wh = (_Float16*)d_ws;
    _Float16* Wl = (_Float16*)((char*)d_ws + szW16);
    _Float16* Ah = (_Float16*)((char*)d_ws + 2 * szW16);
    float* grad = (float*)((char*)d_ws + 2 * szW16 + szA16);
    float* logfwd = (float*)((char*)grad + szGrad);
    int* idxs = (int*)(logfwd + BATCH);

    split_w_kernel<<<DIM * DIM / 4 / 256, 256, 0, stream>>>(W, Wh, Wl);
    conv_f16_kernel<<<BATCH * DIM / 4 / 256, 256, 0, stream>>>(x, Ah);
    gemm_f16_kernel<<<dim3(DIM / GBN, BATCH / GBM), 256, 0, stream>>>(Ah, Wh, Wl, bvec, grad);
    scan_kernel<<<BATCH, 256, 0, stream>>>(x, bvec, grad, out, idxs, logfwd, K);
    conv_f16_kernel<<<BATCH * DIM / 4 / 256, 256, 0, stream>>>(out, Ah);
    gemm_f16_kernel<<<dim3(DIM / GBN, BATCH / GBM), 256, 0, stream>>>(Ah, Wh, Wl, bvec, grad);
    bwd_kernel<<<BATCH, 256, 0, stream>>>(x, bvec, grad, out, idxs, logfwd, K);
  } else {
    float* grad = (float*)d_ws;
    float* logfwd = grad + (size_t)BATCH * DIM;
    int* idxs = (int*)(logfwd + BATCH);
    dim3 gg(DIM / 64, BATCH / 64);
    gemm_bias_kernel<<<gg, 256, 0, stream>>>(x, W, bvec, grad);
    scan_kernel<<<BATCH, 256, 0, stream>>>(x, bvec, grad, out, idxs, logfwd, K);
    gemm_bias_kernel<<<gg, 256, 0, stream>>>(out, W, bvec, grad);
    bwd_kernel<<<BATCH, 256, 0, stream>>>(x, bvec, grad, out, idxs, logfwd, K);
  }
}